// Round 3
// baseline (16821.974 us; speedup 1.0000x reference)
//
#include <hip/hip_runtime.h>
#include <math.h>

// ---- problem constants ----
#define Bn 32
#define Sn 197
#define Dn 768
#define Hn 12
#define DHn 64
#define Fn 3072
#define Ln 12
#define NPATCH 196
#define NCLSn 1000
#define MTOK (Bn * Sn)   // 6304

typedef __attribute__((ext_vector_type(8))) short short8;
typedef __attribute__((ext_vector_type(4))) float f32x4;

__device__ __forceinline__ unsigned short f2bf(float f) {
  union { float f; unsigned int u; } v; v.f = f;
  unsigned int r = v.u + 0x7fffu + ((v.u >> 16) & 1u);
  return (unsigned short)(r >> 16);
}
__device__ __forceinline__ float bf2f(unsigned short h) {
  union { unsigned int u; float f; } v; v.u = ((unsigned int)h) << 16;
  return v.f;
}

// ---- transpose + cast fp32[rows][cols] -> bf16[cols][rows] ----
__global__ __launch_bounds__(256) void transpose_cast(
    const float* __restrict__ in, unsigned short* __restrict__ out,
    int rows, int cols) {
  __shared__ float tile[32][33];
  int c0 = blockIdx.x * 32, r0 = blockIdx.y * 32;
  int tx = threadIdx.x, ty = threadIdx.y;
  for (int i = 0; i < 32; i += 8) {
    int r = r0 + ty + i, c = c0 + tx;
    tile[ty + i][tx] = (r < rows && c < cols) ? in[(size_t)r * cols + c] : 0.f;
  }
  __syncthreads();
  for (int i = 0; i < 32; i += 8) {
    int c = c0 + ty + i, r = r0 + tx;
    if (c < cols && r < rows)
      out[(size_t)c * rows + r] = f2bf(tile[tx][ty + i]);
  }
}

// ---- batched 768x768 transpose of 4 weights (Wq,Wk,Wv,Wo of one layer) ----
__global__ __launch_bounds__(256) void transpose_cast4(
    const float* __restrict__ i0, const float* __restrict__ i1,
    const float* __restrict__ i2, const float* __restrict__ i3,
    unsigned short* __restrict__ out) {
  __shared__ float tile[32][33];
  int z = blockIdx.z;
  const float* in = (z == 0) ? i0 : (z == 1) ? i1 : (z == 2) ? i2 : i3;
  unsigned short* o = out + (size_t)z * Dn * Dn;
  int c0 = blockIdx.x * 32, r0 = blockIdx.y * 32;
  int tx = threadIdx.x, ty = threadIdx.y;
  for (int i = 0; i < 32; i += 8)
    tile[ty + i][tx] = in[(size_t)(r0 + ty + i) * Dn + c0 + tx];
  __syncthreads();
  for (int i = 0; i < 32; i += 8)
    o[(size_t)(c0 + ty + i) * Dn + r0 + tx] = f2bf(tile[tx][ty + i]);
}

// ---- plain cast fp32 -> bf16 ----
__global__ __launch_bounds__(256) void cast_bf(
    const float* __restrict__ in, unsigned short* __restrict__ out, int n) {
  int i = blockIdx.x * 256 + threadIdx.x;
  if (i < n) out[i] = f2bf(in[i]);
}

// ---- build concatenated qkv bias [L][2304] fp32 ----
__global__ __launch_bounds__(256) void build_qkvb(
    const float* __restrict__ bq, const float* __restrict__ bk,
    const float* __restrict__ bv, float* __restrict__ qkvb) {
  int i = blockIdx.x * 256 + threadIdx.x;
  if (i >= Ln * 3 * Dn) return;
  int l = i / (3 * Dn), r = i % (3 * Dn);
  int slice = r / Dn, d = r % Dn;
  const float* src = (slice == 0) ? bq : (slice == 1) ? bk : bv;
  qkvb[i] = src[(size_t)l * Dn + d];
}

// ---- im2col: X[B,3,224,224] -> A[b*196+hp*14+wp][c*256+p*16+q] bf16 ----
__global__ __launch_bounds__(256) void im2col_patches(
    const float* __restrict__ X, unsigned short* __restrict__ A) {
  int idx = blockIdx.x * 256 + threadIdx.x;
  if (idx >= NPATCH * Bn * Dn) return;
  int col = idx % Dn, row = idx / Dn;
  int b = row / NPATCH, pi = row % NPATCH;
  int hp = pi / 14, wp = pi % 14;
  int c = col >> 8, r2 = col & 255, p = r2 >> 4, q = r2 & 15;
  A[idx] = f2bf(X[(((size_t)b * 3 + c) * 224 + hp * 16 + p) * 224 + wp * 16 + q]);
}

// ---- x[b][0][:] = cls_token + pos_emb[0] ----
__global__ __launch_bounds__(256) void init_cls(
    const float* __restrict__ cls_tok, const float* __restrict__ pos_emb,
    float* __restrict__ x) {
  int i = blockIdx.x * 256 + threadIdx.x;
  if (i >= Bn * Dn) return;
  int b = i / Dn, d = i % Dn;
  x[(size_t)b * Sn * Dn + d] = cls_tok[d] + pos_emb[d];
}

// ---- LayerNorm over D=768; out bf16 ----
__global__ __launch_bounds__(256) void layernorm_k(
    const float* __restrict__ x, int row_stride,
    const float* __restrict__ g, const float* __restrict__ b,
    unsigned short* __restrict__ out) {
  int row = blockIdx.x, t = threadIdx.x;
  const float* xr = x + (size_t)row * row_stride;
  float v0 = xr[t], v1 = xr[t + 256], v2 = xr[t + 512];
  float s = v0 + v1 + v2;
  __shared__ float red[4];
  int lane = t & 63, wid = t >> 6;
  for (int off = 32; off > 0; off >>= 1) s += __shfl_xor(s, off, 64);
  if (lane == 0) red[wid] = s;
  __syncthreads();
  float mean = (red[0] + red[1] + red[2] + red[3]) * (1.f / 768.f);
  __syncthreads();
  float d0 = v0 - mean, d1 = v1 - mean, d2 = v2 - mean;
  float q = d0 * d0 + d1 * d1 + d2 * d2;
  for (int off = 32; off > 0; off >>= 1) q += __shfl_xor(q, off, 64);
  if (lane == 0) red[wid] = q;
  __syncthreads();
  float var = (red[0] + red[1] + red[2] + red[3]) * (1.f / 768.f);
  float rstd = rsqrtf(var + 1e-5f);
  size_t o = (size_t)row * Dn;
  out[o + t]       = f2bf(d0 * rstd * g[t]       + b[t]);
  out[o + t + 256] = f2bf(d1 * rstd * g[t + 256] + b[t + 256]);
  out[o + t + 512] = f2bf(d2 * rstd * g[t + 512] + b[t + 512]);
}

// =====================================================================
// gemm128: C[M][N] = A[M][K](bf16) * Bt[N][K](bf16)^T
// 128x128 block tile, BK=32, 4 waves (64x64 wave tile, acc[4][4]),
// global_load_lds width=16 staging (m97 structure). N must be /128;
// M-tail handled by clamping staged rows (garbage only in unwritten C rows).
// MODE 0: fused qkv: out bf16 [3][B][H][S][DH]   (bias = qkvb row)
// MODE 1: out fp32 [M][N] = acc+bias+res
// MODE 2: out bf16 [M][N] = gelu(acc+bias)
// MODE 3: patch: out fp32 x[b][1+pi][n] = acc+bias+pos_emb[(1+pi)*D+n]
// =====================================================================
template <int MODE>
__global__ __launch_bounds__(256) void gemm128(
    const unsigned short* __restrict__ A, const unsigned short* __restrict__ Bt,
    const float* __restrict__ bias, const float* __restrict__ res,
    float* __restrict__ Cf, unsigned short* __restrict__ Cb,
    int M, int N, int K) {
  __shared__ unsigned short As[128 * 32];   // 8 KB
  __shared__ unsigned short Bs[128 * 32];   // 8 KB
  int m0 = blockIdx.x * 128, n0 = blockIdx.y * 128;
  int tid = threadIdx.x, lane = tid & 63, wid = tid >> 6;
  int wm = (wid >> 1) * 64, wn = (wid & 1) * 64;
  int col = lane & 15, quad = lane >> 4;

  // staging: thread -> (row = tid>>2, seg = (tid&3)*8 elems); lds byte = tid*16
  int sr = tid >> 2, ss = (tid & 3) * 8;
  int ma0 = m0 + sr;      if (ma0 >= M) ma0 = M - 1;
  int ma1 = m0 + 64 + sr; if (ma1 >= M) ma1 = M - 1;
  const unsigned short* gA0 = A + (size_t)ma0 * K + ss;
  const unsigned short* gA1 = A + (size_t)ma1 * K + ss;
  const unsigned short* gB0 = Bt + (size_t)(n0 + sr) * K + ss;
  const unsigned short* gB1 = Bt + (size_t)(n0 + 64 + sr) * K + ss;
  char* lA0 = (char*)As + wid * 1024;
  char* lA1 = (char*)As + 4096 + wid * 1024;
  char* lB0 = (char*)Bs + wid * 1024;
  char* lB1 = (char*)Bs + 4096 + wid * 1024;

  f32x4 acc[4][4] = {};
  for (int k0 = 0; k0 < K; k0 += 32) {
    __builtin_amdgcn_global_load_lds(
        (const __attribute__((address_space(1))) void*)(gA0 + k0),
        (__attribute__((address_space(3))) void*)lA0, 16, 0, 0);
    __builtin_amdgcn_global_load_lds(
        (const __attribute__((address_space(1))) void*)(gA1 + k0),
        (__attribute__((address_space(3))) void*)lA1, 16, 0, 0);
    __builtin_amdgcn_global_load_lds(
        (const __attribute__((address_space(1))) void*)(gB0 + k0),
        (__attribute__((address_space(3))) void*)lB0, 16, 0, 0);
    __builtin_amdgcn_global_load_lds(
        (const __attribute__((address_space(1))) void*)(gB1 + k0),
        (__attribute__((address_space(3))) void*)lB1, 16, 0, 0);
    __syncthreads();
    short8 af[4], bf[4];
    for (int i = 0; i < 4; i++)
      af[i] = *(const short8*)((char*)As + (wm + i * 16 + col) * 64 + quad * 16);
    for (int j = 0; j < 4; j++)
      bf[j] = *(const short8*)((char*)Bs + (wn + j * 16 + col) * 64 + quad * 16);
    for (int i = 0; i < 4; i++)
      for (int j = 0; j < 4; j++)
        acc[i][j] = __builtin_amdgcn_mfma_f32_16x16x32_bf16(af[i], bf[j], acc[i][j], 0, 0, 0);
    __syncthreads();
  }

  for (int i = 0; i < 4; i++)
    for (int j = 0; j < 4; j++)
      for (int r = 0; r < 4; r++) {
        int gm = m0 + wm + i * 16 + quad * 4 + r;
        int gn = n0 + wn + j * 16 + col;
        if (gm >= M) continue;
        float val = acc[i][j][r] + bias[gn];
        if constexpr (MODE == 0) {
          int slice = gn / Dn;            // 0=q 1=k 2=v
          int b = gm / Sn, s = gm % Sn;
          int h = (gn >> 6) % Hn, dh = gn & 63;
          Cb[((((size_t)slice * Bn + b) * Hn + h) * Sn + s) * DHn + dh] = f2bf(val);
        } else if constexpr (MODE == 1) {
          size_t o = (size_t)gm * N + gn;
          Cf[o] = val + res[o];
        } else if constexpr (MODE == 2) {
          float gl = 0.5f * val * (1.f + erff(val * 0.70710678118654752f));
          Cb[(size_t)gm * N + gn] = f2bf(gl);
        } else {
          int b = gm / NPATCH, pi = gm % NPATCH;
          Cf[((size_t)b * Sn + 1 + pi) * Dn + gn] =
              val + res[(size_t)(1 + pi) * Dn + gn];
        }
      }
}

// ---- small GEMM for the classifier head: C[M][N] = A*Bt^T + bias ----
__global__ __launch_bounds__(256) void gemm64_head(
    const unsigned short* __restrict__ A, const unsigned short* __restrict__ Bt,
    const float* __restrict__ bias, float* __restrict__ Cf,
    int M, int N, int K) {
  __shared__ unsigned short As[64][32];
  __shared__ unsigned short Bs[64][32];
  int m0 = blockIdx.x * 64, n0 = blockIdx.y * 64;
  int tid = threadIdx.x;
  int wid = tid >> 6, lane = tid & 63;
  int wm = (wid >> 1) * 32, wn = (wid & 1) * 32;
  int lrow = lane & 15, lq = lane >> 4;
  int lr = tid >> 2, lseg = (tid & 3) * 8;
  f32x4 acc[2][2] = {};
  for (int k0 = 0; k0 < K; k0 += 32) {
    int gm = m0 + lr;
    uint4 av = (gm < M) ? *(const uint4*)(A + (size_t)gm * K + k0 + lseg)
                        : make_uint4(0, 0, 0, 0);
    int gn = n0 + lr;
    uint4 bv = (gn < N) ? *(const uint4*)(Bt + (size_t)gn * K + k0 + lseg)
                        : make_uint4(0, 0, 0, 0);
    __syncthreads();
    *(uint4*)(&As[lr][lseg]) = av;
    *(uint4*)(&Bs[lr][lseg]) = bv;
    __syncthreads();
    short8 a0 = *(const short8*)(&As[wm + lrow][lq * 8]);
    short8 a1 = *(const short8*)(&As[wm + 16 + lrow][lq * 8]);
    short8 b0 = *(const short8*)(&Bs[wn + lrow][lq * 8]);
    short8 b1 = *(const short8*)(&Bs[wn + 16 + lrow][lq * 8]);
    acc[0][0] = __builtin_amdgcn_mfma_f32_16x16x32_bf16(a0, b0, acc[0][0], 0, 0, 0);
    acc[0][1] = __builtin_amdgcn_mfma_f32_16x16x32_bf16(a0, b1, acc[0][1], 0, 0, 0);
    acc[1][0] = __builtin_amdgcn_mfma_f32_16x16x32_bf16(a1, b0, acc[1][0], 0, 0, 0);
    acc[1][1] = __builtin_amdgcn_mfma_f32_16x16x32_bf16(a1, b1, acc[1][1], 0, 0, 0);
  }
  for (int tm = 0; tm < 2; tm++)
    for (int tn = 0; tn < 2; tn++)
      for (int r = 0; r < 4; r++) {
        int gm = m0 + wm + tm * 16 + lq * 4 + r;
        int gn = n0 + wn + tn * 16 + lrow;
        if (gm >= M || gn >= N) continue;
        Cf[(size_t)gm * N + gn] = acc[tm][tn][r] + bias[gn];
      }
}

// ---- MFMA flash-style attention (unchanged from round 2) ----
#define QT 16
#define NKT 13
#define PJ 232
__global__ __launch_bounds__(256) void attn_mfma(
    const unsigned short* __restrict__ q, const unsigned short* __restrict__ k,
    const unsigned short* __restrict__ v, unsigned short* __restrict__ out) {
  int bh = blockIdx.x, b = bh / Hn, h = bh % Hn;
  const unsigned short* qp = q + (size_t)bh * Sn * DHn;
  const unsigned short* kp = k + (size_t)bh * Sn * DHn;
  const unsigned short* vp = v + (size_t)bh * Sn * DHn;
  __shared__ unsigned short Vt[DHn][PJ];
  __shared__ unsigned short Pl[4][QT][PJ];
  int t = threadIdx.x, lane = t & 63, wid = t >> 6;
  int col = lane & 15, quad = lane >> 4;
  for (int i = t; i < Sn * DHn; i += 256) {
    int j = i >> 6, d = i & 63;
    Vt[d][j] = vp[i];
  }
  for (int i = t; i < DHn * (PJ - Sn); i += 256) {
    int d = i / (PJ - Sn), j = Sn + i % (PJ - Sn);
    Vt[d][j] = 0;
  }
  for (int i = lane; i < QT * (PJ - NKT * 16); i += 64) {
    int r = i / (PJ - NKT * 16), c = NKT * 16 + i % (PJ - NKT * 16);
    Pl[wid][r][c] = 0;
  }
  __syncthreads();

  for (int qt = wid; qt < NKT; qt += 4) {
    int q0 = qt * QT;
    int qrow = q0 + col;
    int qc = (qrow < Sn) ? qrow : (Sn - 1);
    short8 qa0 = *(const short8*)(qp + (size_t)qc * DHn + quad * 8);
    short8 qa1 = *(const short8*)(qp + (size_t)qc * DHn + 32 + quad * 8);

    f32x4 sc[NKT];
    for (int kt = 0; kt < NKT; kt++) {
      int krow = kt * QT + col;
      int kc = (krow < Sn) ? krow : (Sn - 1);
      short8 kb0 = *(const short8*)(kp + (size_t)kc * DHn + quad * 8);
      short8 kb1 = *(const short8*)(kp + (size_t)kc * DHn + 32 + quad * 8);
      f32x4 c = {};
      c = __builtin_amdgcn_mfma_f32_16x16x32_bf16(qa0, kb0, c, 0, 0, 0);
      c = __builtin_amdgcn_mfma_f32_16x16x32_bf16(qa1, kb1, c, 0, 0, 0);
      if (krow >= Sn)
        for (int r = 0; r < 4; r++) c[r] = -1e30f;
      sc[kt] = c;
    }

    for (int r = 0; r < 4; r++) {
      float m = -1e30f;
      for (int kt = 0; kt < NKT; kt++) m = fmaxf(m, sc[kt][r]);
      for (int off = 1; off < 16; off <<= 1) m = fmaxf(m, __shfl_xor(m, off, 64));
      float s = 0.f;
      for (int kt = 0; kt < NKT; kt++) {
        float e = __expf((sc[kt][r] - m) * 0.125f);
        sc[kt][r] = e;
        s += e;
      }
      for (int off = 1; off < 16; off <<= 1) s += __shfl_xor(s, off, 64);
      float inv = 1.f / s;
      int row = quad * 4 + r;
      for (int kt = 0; kt < NKT; kt++)
        Pl[wid][row][kt * 16 + col] = f2bf(sc[kt][r] * inv);
    }

    f32x4 o[4] = {};
    for (int jc = 0; jc < 7; jc++) {
      short8 pa = *(const short8*)(&Pl[wid][col][jc * 32 + quad * 8]);
      for (int dt = 0; dt < 4; dt++) {
        short8 vb = *(const short8*)(&Vt[dt * 16 + col][jc * 32 + quad * 8]);
        o[dt] = __builtin_amdgcn_mfma_f32_16x16x32_bf16(pa, vb, o[dt], 0, 0, 0);
      }
    }

    for (int dt = 0; dt < 4; dt++)
      for (int r = 0; r < 4; r++) {
        int qq = q0 + quad * 4 + r;
        if (qq < Sn)
          out[((size_t)b * Sn + qq) * Dn + h * DHn + dt * 16 + col] =
              f2bf(o[dt][r]);
      }
  }
}

extern "C" void kernel_launch(void* const* d_in, const int* in_sizes, int n_in,
                              void* d_out, int out_size, void* d_ws, size_t ws_size,
                              hipStream_t stream) {
  const float* X       = (const float*)d_in[0];
  const float* patch_w = (const float*)d_in[1];
  const float* patch_b = (const float*)d_in[2];
  const float* cls_tok = (const float*)d_in[3];
  const float* pos_emb = (const float*)d_in[4];
  const float* ln1_g = (const float*)d_in[5];
  const float* ln1_b = (const float*)d_in[6];
  const float* Wq = (const float*)d_in[7];
  const float* bq = (const float*)d_in[8];
  const float* Wk = (const float*)d_in[9];
  const float* bk = (const float*)d_in[10];
  const float* Wv = (const float*)d_in[11];
  const float* bv = (const float*)d_in[12];
  const float* Wo = (const float*)d_in[13];
  const float* bo = (const float*)d_in[14];
  const float* ln2_g = (const float*)d_in[15];
  const float* ln2_b = (const float*)d_in[16];
  const float* Wf1 = (const float*)d_in[17];
  const float* bf1 = (const float*)d_in[18];
  const float* Wf2 = (const float*)d_in[19];
  const float* bf2 = (const float*)d_in[20];
  const float* lnf_g = (const float*)d_in[21];
  const float* lnf_b = (const float*)d_in[22];
  const float* head_w = (const float*)d_in[23];
  const float* head_b = (const float*)d_in[24];
  float* out = (float*)d_out;

  char* base = (char*)d_ws;
  size_t off = 0;
  auto alloc = [&](size_t bytes) -> void* {
    void* p = base + off;
    off += (bytes + 255) & ~(size_t)255;
    return p;
  };
  unsigned short* wqkvo_t = (unsigned short*)alloc((size_t)4 * Dn * Dn * 2);
  unsigned short* wf1_t = (unsigned short*)alloc((size_t)Dn * Fn * 2);
  unsigned short* wf2_t = (unsigned short*)alloc((size_t)Dn * Fn * 2);
  unsigned short* pw_bf = (unsigned short*)alloc((size_t)Dn * Dn * 2);
  unsigned short* hw_t  = (unsigned short*)alloc((size_t)NCLSn * Dn * 2);
  unsigned short* im2c  = (unsigned short*)alloc((size_t)Bn * NPATCH * Dn * 2);
  float*          x     = (float*)alloc((size_t)MTOK * Dn * 4);
  unsigned short* h_bf  = (unsigned short*)alloc((size_t)MTOK * Dn * 2);
  unsigned short* qkv   = (unsigned short*)alloc((size_t)3 * MTOK * Dn * 2);
  unsigned short* atob  = (unsigned short*)alloc((size_t)MTOK * Dn * 2);
  unsigned short* gel   = (unsigned short*)alloc((size_t)MTOK * Fn * 2);
  unsigned short* clsb  = (unsigned short*)alloc((size_t)Bn * Dn * 2);
  float*          qkvb  = (float*)alloc((size_t)Ln * 3 * Dn * 4);
  (void)ws_size; (void)in_sizes; (void)n_in; (void)out_size;

  unsigned short* qb = qkv;
  unsigned short* kb = qkv + (size_t)MTOK * Dn;
  unsigned short* vb = qkv + (size_t)2 * MTOK * Dn;

  dim3 tb(32, 8);
  auto tgrid = [](int rows, int cols) { return dim3((cols + 31) / 32, (rows + 31) / 32); };
  auto g128 = [](int M, int N) { return dim3((M + 127) / 128, N / 128); };

  // prologue
  cast_bf<<<(Dn * Dn + 255) / 256, 256, 0, stream>>>(patch_w, pw_bf, Dn * Dn);
  transpose_cast<<<tgrid(Dn, NCLSn), tb, 0, stream>>>(head_w, hw_t, Dn, NCLSn);
  build_qkvb<<<(Ln * 3 * Dn + 255) / 256, 256, 0, stream>>>(bq, bk, bv, qkvb);
  im2col_patches<<<(Bn * NPATCH * Dn + 255) / 256, 256, 0, stream>>>(X, im2c);
  init_cls<<<(Bn * Dn + 255) / 256, 256, 0, stream>>>(cls_tok, pos_emb, x);
  gemm128<3><<<g128(Bn * NPATCH, Dn), 256, 0, stream>>>(
      im2c, pw_bf, patch_b, pos_emb, x, nullptr, Bn * NPATCH, Dn, Dn);

  for (int l = 0; l < Ln; l++) {
    const size_t wo_off = (size_t)l * Dn * Dn;
    const size_t wf_off = (size_t)l * Dn * Fn;
    transpose_cast4<<<dim3(24, 24, 4), tb, 0, stream>>>(
        Wq + wo_off, Wk + wo_off, Wv + wo_off, Wo + wo_off, wqkvo_t);
    transpose_cast<<<tgrid(Dn, Fn), tb, 0, stream>>>(Wf1 + wf_off, wf1_t, Dn, Fn);
    transpose_cast<<<tgrid(Fn, Dn), tb, 0, stream>>>(Wf2 + wf_off, wf2_t, Fn, Dn);

    layernorm_k<<<MTOK, 256, 0, stream>>>(x, Dn, ln1_g + (size_t)l * Dn,
                                          ln1_b + (size_t)l * Dn, h_bf);
    // fused QKV: N = 2304
    gemm128<0><<<g128(MTOK, 3 * Dn), 256, 0, stream>>>(
        h_bf, wqkvo_t, qkvb + (size_t)l * 3 * Dn, nullptr, nullptr, qkv,
        MTOK, 3 * Dn, Dn);
    attn_mfma<<<Bn * Hn, 256, 0, stream>>>(qb, kb, vb, atob);
    gemm128<1><<<g128(MTOK, Dn), 256, 0, stream>>>(
        atob, wqkvo_t + (size_t)3 * Dn * Dn, bo + (size_t)l * Dn, x, x, nullptr,
        MTOK, Dn, Dn);
    layernorm_k<<<MTOK, 256, 0, stream>>>(x, Dn, ln2_g + (size_t)l * Dn,
                                          ln2_b + (size_t)l * Dn, h_bf);
    gemm128<2><<<g128(MTOK, Fn), 256, 0, stream>>>(
        h_bf, wf1_t, bf1 + (size_t)l * Fn, nullptr, nullptr, gel, MTOK, Fn, Dn);
    gemm128<1><<<g128(MTOK, Dn), 256, 0, stream>>>(
        gel, wf2_t, bf2 + (size_t)l * Dn, x, x, nullptr, MTOK, Dn, Fn);
  }

  layernorm_k<<<Bn, 256, 0, stream>>>(x, Sn * Dn, lnf_g, lnf_b, clsb);
  gemm64_head<<<dim3(1, (NCLSn + 63) / 64), 256, 0, stream>>>(
      clsb, hw_t, head_b, out, Bn, NCLSn, Dn);
}